// Round 11
// baseline (344.136 us; speedup 1.0000x reference)
//
#include <hip/hip_runtime.h>
#include <hip/hip_bf16.h>
#include <math.h>

#define NN 20000      // nodes
#define ER 640000     // raw edges
#define ET 660000     // edges incl. self loops
#define D1 128
#define D2 256
#define EPSV 1e-5f
#define SLOPE 0.2f
#define NT1 313       // ceil(NN/64) gemm1 row tiles
#define NHIST 64      // histogram units
#define HCH 10000     // edges per unit (ushort pack: max count 10000 < 65536)
#define AGB 2048      // persistent agg blocks (x4 waves = 8192 waves)

typedef __attribute__((ext_vector_type(8))) short bf16x8;
typedef __attribute__((ext_vector_type(4))) float f32x4;

// ---------- helpers ----------
__device__ __forceinline__ int detect64(const void* ei) {
  const int* p = (const int*)ei;
  return (p[1] | p[3] | p[5] | p[7]) == 0;
}
__device__ __forceinline__ int clampn(int v) { return v < 0 ? 0 : (v >= NN ? NN-1 : v); }
__device__ __forceinline__ float bf16_lo(unsigned int u){ return __uint_as_float(u<<16); }
__device__ __forceinline__ float bf16_hi(unsigned int u){ return __uint_as_float(u & 0xffff0000u); }

// ---------- degree histogram: 64 LDS-private ushort-packed units ----------
__global__ void k_hist(const void* ei, unsigned int* dpart, int* gcount) {
  extern __shared__ unsigned int hist[];     // HCH uints = 2 nodes/uint
  int db = blockIdx.x, t = threadIdx.x;
  if (db == 0 && t == 0) *gcount = 0;
  for (int i = t; i < HCH; i += 256) hist[i] = 0;
  __syncthreads();
  int base = db * HCH;
  if (detect64(ei)) {
    const long long* q = (const long long*)ei + ER;
    for (int i = base + t; i < base + HCH; i += 256) {
      int d = clampn((int)q[i]);
      atomicAdd(&hist[d>>1], 1u << ((d&1)*16));
    }
  } else {
    const int* q = (const int*)ei + ER;
    for (int i = base + t; i < base + HCH; i += 256) {
      int d = clampn(q[i]);
      atomicAdd(&hist[d>>1], 1u << ((d&1)*16));
    }
  }
  __syncthreads();
  for (int i = t; i < HCH; i += 256) dpart[(size_t)db*HCH + i] = hist[i];
}

// ---------- parallel segment allocator + BN accumulator zeroing ----------
__global__ __launch_bounds__(256) void k_alloc(const unsigned int* dpart, int* begv, int* endv,
                                               int* cursor, int* gcount, float* bnz) {
  __shared__ int wsum[4], wbase[4];
  int gid = blockIdx.x*256 + threadIdx.x;
  if (gid < 768) bnz[gid] = 0.f;            // bns1|bnq1|bns2|bnq2
  int d = 0;
  if (gid < NN) {
    d = 1;                                   // self loop
    int half = (gid & 1) * 16;
    int idx = gid >> 1;
    for (int db = 0; db < NHIST; db++)
      d += (dpart[(size_t)db*HCH + idx] >> half) & 0xffff;
  }
  int lane = threadIdx.x & 63, w = threadIdx.x >> 6;
  int v = d;
  #pragma unroll
  for (int o = 1; o < 64; o <<= 1) {
    int u = __shfl_up(v, o);
    if (lane >= o) v += u;
  }
  if (lane == 63) wsum[w] = v;
  __syncthreads();
  if (threadIdx.x == 0) {
    int s0 = wsum[0], s1 = wsum[1], s2 = wsum[2], s3 = wsum[3];
    int b = atomicAdd(gcount, s0 + s1 + s2 + s3);
    wbase[0] = b; wbase[1] = b + s0; wbase[2] = b + s0 + s1; wbase[3] = b + s0 + s1 + s2;
  }
  __syncthreads();
  if (gid < NN) {
    int beg = wbase[w] + v - d;
    begv[gid] = beg; cursor[gid] = beg; endv[gid] = beg + d;
  }
}

// ---------- merged: gemm1 tiles (inline W1 cast) + scatter ----------
__global__ __launch_bounds__(256) void k_gs(const float* x, const float* W1,
                                            const float* att_s1, const float* att_d1,
                                            __hip_bfloat16* hxb, float2* as1, float2* ad1,
                                            const void* ei, int* cursor, int* srcs) {
  __shared__ __hip_bfloat16 As[64][72];
  __shared__ __hip_bfloat16 Bs[128][72];
  __shared__ float asred[4][64], adred[4][64];
  int b = blockIdx.x, t = threadIdx.x;
  if (b >= NT1) {
    // ------- scatter role -------
    int i0 = ((b - NT1)*256 + t)*4;
    if (i0 >= ET) return;
    int s[4], d[4];
    if (i0 >= ER) {
      #pragma unroll
      for (int k = 0; k < 4; k++) { s[k] = i0 + k - ER; d[k] = s[k]; }
    } else if (detect64(ei)) {
      const long long* p64 = (const long long*)ei;
      uint4 qa = *(const uint4*)(p64 + i0);
      uint4 qb = *(const uint4*)(p64 + i0 + 2);
      uint4 ra = *(const uint4*)(p64 + ER + i0);
      uint4 rb = *(const uint4*)(p64 + ER + i0 + 2);
      s[0]=clampn((int)qa.x); s[1]=clampn((int)qa.z); s[2]=clampn((int)qb.x); s[3]=clampn((int)qb.z);
      d[0]=clampn((int)ra.x); d[1]=clampn((int)ra.z); d[2]=clampn((int)rb.x); d[3]=clampn((int)rb.z);
    } else {
      const int* p32 = (const int*)ei;
      uint4 qs = *(const uint4*)(p32 + i0);
      uint4 qd = *(const uint4*)(p32 + ER + i0);
      s[0]=clampn((int)qs.x); s[1]=clampn((int)qs.y); s[2]=clampn((int)qs.z); s[3]=clampn((int)qs.w);
      d[0]=clampn((int)qd.x); d[1]=clampn((int)qd.y); d[2]=clampn((int)qd.z); d[3]=clampn((int)qd.w);
    }
    #pragma unroll
    for (int k = 0; k < 4; k++) {
      int pos = atomicAdd(&cursor[d[k]], 1);
      srcs[pos] = s[k];
    }
    return;
  }
  // ------- gemm1 role -------
  int m0 = b * 64;
  for (int i = t; i < 512; i += 256) {       // stage x fp32->bf16
    int r = i >> 3, s = i & 7;
    int gr = m0 + r; if (gr >= NN) gr = NN - 1;
    float4 f0 = ((const float4*)(x + (size_t)gr*64))[s*2];
    float4 f1 = ((const float4*)(x + (size_t)gr*64))[s*2+1];
    __hip_bfloat16 hb[8] = {
      __float2bfloat16(f0.x), __float2bfloat16(f0.y), __float2bfloat16(f0.z), __float2bfloat16(f0.w),
      __float2bfloat16(f1.x), __float2bfloat16(f1.y), __float2bfloat16(f1.z), __float2bfloat16(f1.w)};
    *(uint4*)&As[r][s*8] = *(uint4*)hb;
  }
  for (int i = t; i < 8192; i += 256) {      // Bs[n][k] = bf16(W1[k][n]) inline transpose-cast
    int n = i & 127, k = i >> 7;
    Bs[n][k] = __float2bfloat16(W1[k*128 + n]);
  }
  __syncthreads();
  int w = t >> 6, lane = t & 63, lm = lane & 15, q = lane >> 4;
  f32x4 acc[4][2];
  #pragma unroll
  for (int rt = 0; rt < 4; rt++)
    #pragma unroll
    for (int ct = 0; ct < 2; ct++) acc[rt][ct] = (f32x4){0.f,0.f,0.f,0.f};
  #pragma unroll
  for (int kc = 0; kc < 2; kc++) {
    bf16x8 bfr[2];
    #pragma unroll
    for (int ct = 0; ct < 2; ct++)
      bfr[ct] = *(const bf16x8*)&Bs[w*32 + ct*16 + lm][kc*32 + q*8];
    #pragma unroll
    for (int rt = 0; rt < 4; rt++) {
      bf16x8 a = *(const bf16x8*)&As[rt*16 + lm][kc*32 + q*8];
      acc[rt][0] = __builtin_amdgcn_mfma_f32_16x16x32_bf16(a, bfr[0], acc[rt][0], 0, 0, 0);
      acc[rt][1] = __builtin_amdgcn_mfma_f32_16x16x32_bf16(a, bfr[1], acc[rt][1], 0, 0, 0);
    }
  }
  #pragma unroll
  for (int rt = 0; rt < 4; rt++)
    #pragma unroll
    for (int ct = 0; ct < 2; ct++)
      #pragma unroll
      for (int rg = 0; rg < 4; rg++) {
        int row = m0 + rt*16 + q*4 + rg;
        int col = w*32 + ct*16 + lm;
        if (row < NN) hxb[(size_t)row*128 + col] = __float2bfloat16(acc[rt][ct][rg]);
      }
  float asc[2], adc[2];
  #pragma unroll
  for (int ct = 0; ct < 2; ct++) {
    int col = w*32 + ct*16 + lm;
    asc[ct] = att_s1[col]; adc[ct] = att_d1[col];
  }
  #pragma unroll
  for (int rt = 0; rt < 4; rt++)
    #pragma unroll
    for (int rg = 0; rg < 4; rg++) {
      float ps = acc[rt][0][rg]*asc[0] + acc[rt][1][rg]*asc[1];
      float pd = acc[rt][0][rg]*adc[0] + acc[rt][1][rg]*adc[1];
      #pragma unroll
      for (int o = 1; o < 16; o <<= 1) { ps += __shfl_xor(ps, o); pd += __shfl_xor(pd, o); }
      if (lm == 0) { int row = rt*16 + q*4 + rg; asred[w][row] = ps; adred[w][row] = pd; }
    }
  __syncthreads();
  if (t < 64) {
    int row = m0 + t;
    if (row < NN) {
      as1[row] = make_float2(asred[0][t] + asred[1][t], asred[2][t] + asred[3][t]);
      ad1[row] = make_float2(adred[0][t] + adred[1][t], adred[2][t] + adred[3][t]);
    }
  }
}

// ---------- MFMA GEMM2: out1 -> BN1+ReLU+cast -> @W2 (inline cast) -> hx2b + att2 ----------
__global__ __launch_bounds__(256) void k_gemm2f(const float* out1, const float* W2,
                                                const float* bns1, const float* bnq1,
                                                const float* gamma1, const float* beta1,
                                                const float* att_s2, const float* att_d2,
                                                __hip_bfloat16* hxb, float2* as2, float2* ad2) {
  __shared__ __hip_bfloat16 As[64][136];
  __shared__ __hip_bfloat16 Bs[256][40];
  __shared__ float AB[2][128];
  __shared__ float asred[4][64], adred[4][64];
  int t = threadIdx.x;
  int m0 = blockIdx.x * 64;
  if (t < 128) {
    float mean = bns1[t]*(1.f/NN);
    float var  = bnq1[t]*(1.f/NN) - mean*mean;
    float A = rsqrtf(var + EPSV)*gamma1[t];
    AB[0][t] = A; AB[1][t] = beta1[t] - mean*A;
  }
  __syncthreads();
  for (int i = t; i < 1024; i += 256) {
    int r = i >> 4, s = i & 15;
    int gr = m0 + r; if (gr >= NN) gr = NN - 1;
    float4 f0 = ((const float4*)(out1 + (size_t)gr*128))[s*2];
    float4 f1 = ((const float4*)(out1 + (size_t)gr*128))[s*2+1];
    int c = s*8;
    float v[8] = {f0.x,f0.y,f0.z,f0.w,f1.x,f1.y,f1.z,f1.w};
    __hip_bfloat16 hb[8];
    #pragma unroll
    for (int k = 0; k < 8; k++)
      hb[k] = __float2bfloat16(fmaxf(v[k]*AB[0][c+k] + AB[1][c+k], 0.f));
    *(uint4*)&As[r][s*8] = *(uint4*)hb;
  }
  int w = t >> 6, lane = t & 63, lm = lane & 15, q = lane >> 4;
  f32x4 acc[4][4];
  #pragma unroll
  for (int rt = 0; rt < 4; rt++)
    #pragma unroll
    for (int ct = 0; ct < 4; ct++) acc[rt][ct] = (f32x4){0.f,0.f,0.f,0.f};
  for (int kc = 0; kc < 4; kc++) {
    __syncthreads();
    for (int i = t; i < 8192; i += 256) {     // Bs[n][kk] = bf16(W2[kc*32+kk][n])
      int n = i & 255, kk = i >> 8;
      Bs[n][kk] = __float2bfloat16(W2[(kc*32 + kk)*256 + n]);
    }
    __syncthreads();
    bf16x8 bfr[4];
    #pragma unroll
    for (int ct = 0; ct < 4; ct++)
      bfr[ct] = *(const bf16x8*)&Bs[w*64 + ct*16 + lm][q*8];
    #pragma unroll
    for (int rt = 0; rt < 4; rt++) {
      bf16x8 a = *(const bf16x8*)&As[rt*16 + lm][kc*32 + q*8];
      #pragma unroll
      for (int ct = 0; ct < 4; ct++)
        acc[rt][ct] = __builtin_amdgcn_mfma_f32_16x16x32_bf16(a, bfr[ct], acc[rt][ct], 0, 0, 0);
    }
  }
  #pragma unroll
  for (int rt = 0; rt < 4; rt++)
    #pragma unroll
    for (int ct = 0; ct < 4; ct++)
      #pragma unroll
      for (int rg = 0; rg < 4; rg++) {
        int row = m0 + rt*16 + q*4 + rg;
        int col = w*64 + ct*16 + lm;
        if (row < NN) hxb[(size_t)row*256 + col] = __float2bfloat16(acc[rt][ct][rg]);
      }
  float asc[4], adc[4];
  #pragma unroll
  for (int ct = 0; ct < 4; ct++) {
    int col = w*64 + ct*16 + lm;
    asc[ct] = att_s2[col]; adc[ct] = att_d2[col];
  }
  #pragma unroll
  for (int rt = 0; rt < 4; rt++)
    #pragma unroll
    for (int rg = 0; rg < 4; rg++) {
      float ps = acc[rt][0][rg]*asc[0] + acc[rt][1][rg]*asc[1]
               + acc[rt][2][rg]*asc[2] + acc[rt][3][rg]*asc[3];
      float pd = acc[rt][0][rg]*adc[0] + acc[rt][1][rg]*adc[1]
               + acc[rt][2][rg]*adc[2] + acc[rt][3][rg]*adc[3];
      #pragma unroll
      for (int o = 1; o < 16; o <<= 1) { ps += __shfl_xor(ps, o); pd += __shfl_xor(pd, o); }
      if (lm == 0) { int row = rt*16 + q*4 + rg; asred[w][row] = ps; adred[w][row] = pd; }
    }
  __syncthreads();
  if (t < 64) {
    int row = m0 + t;
    if (row < NN) {
      as2[row] = make_float2(asred[0][t] + asred[1][t], asred[2][t] + asred[3][t]);
      ad2[row] = make_float2(adred[0][t] + adred[1][t], adred[2][t] + adred[3][t]);
    }
  }
}

// ---------- agg1 persistent: 4 waves/block, wave-per-node, fused BN stats ----------
// Wave-private LDS staging; wave_barrier (not __syncthreads) — node loops diverge
// across waves, and wave64 lockstep + compiler may-alias ordering make the
// ds_write -> ds_read sequence safe within one wave.
__global__ __launch_bounds__(256) void k_agg1s(const int* begv, const int* endv, const int* srcs,
                                               const float2* asv, const float2* adv,
                                               const uint4* hx, const float* bias,
                                               float* out, float* bn /* 256: sum|sq */) {
  __shared__ float2 sp[4][2][64];
  __shared__ float bnacc[256];
  int t = threadIdx.x;
  bnacc[t] = 0.f;
  __syncthreads();
  int wid = t >> 6, lane = t & 63;
  int el = lane >> 4, c = lane & 15, h = c >> 3;
  for (int n = blockIdx.x*4 + wid; n < NN; n += AGB*4) {
    float2 ad = adv[n];
    int beg = begv[n], end = endv[n];
    float a[8] = {0.f,0.f,0.f,0.f,0.f,0.f,0.f,0.f};
    float z0 = 0.f, z1 = 0.f;
    for (int cb = beg; cb < end; cb += 64) {
      int len = end - cb; if (len > 64) len = 64;
      if (lane < len) {
        int s = srcs[cb + lane];
        float2 as = asv[s];
        float e0 = as.x + ad.x, e1 = as.y + ad.y;
        e0 = e0 > 0.f ? e0 : SLOPE*e0;
        e1 = e1 > 0.f ? e1 : SLOPE*e1;
        float p0 = __expf(e0), p1 = __expf(e1);
        sp[wid][0][lane] = make_float2(__int_as_float(s), p0);
        sp[wid][1][lane] = make_float2(__int_as_float(s), p1);
        z0 += p0; z1 += p1;
      }
      __builtin_amdgcn_wave_barrier();
      for (int j = 0; j < len; j += 4) {
        int e = j + el;
        if (e < len) {
          float2 v = sp[wid][h][e];
          uint4 u = hx[(size_t)__float_as_int(v.x)*16 + c];
          float pj = v.y;
          a[0] += pj*bf16_lo(u.x); a[1] += pj*bf16_hi(u.x);
          a[2] += pj*bf16_lo(u.y); a[3] += pj*bf16_hi(u.y);
          a[4] += pj*bf16_lo(u.z); a[5] += pj*bf16_hi(u.z);
          a[6] += pj*bf16_lo(u.w); a[7] += pj*bf16_hi(u.w);
        }
      }
      __builtin_amdgcn_wave_barrier();
    }
    #pragma unroll
    for (int k = 0; k < 8; k++) {
      a[k] += __shfl_down(a[k], 32);
      a[k] += __shfl_down(a[k], 16);
    }
    #pragma unroll
    for (int o = 1; o < 64; o <<= 1) { z0 += __shfl_xor(z0, o); z1 += __shfl_xor(z1, o); }
    if (lane < 16) {
      float inv = 1.f / (h ? z1 : z0);
      float4 b0 = ((const float4*)bias)[2*c];
      float4 b1 = ((const float4*)bias)[2*c+1];
      float4 o0 = { a[0]*inv + b0.x, a[1]*inv + b0.y, a[2]*inv + b0.z, a[3]*inv + b0.w };
      float4 o1 = { a[4]*inv + b1.x, a[5]*inv + b1.y, a[6]*inv + b1.z, a[7]*inv + b1.w };
      ((float4*)(out + (size_t)n*D1))[2*c]   = o0;
      ((float4*)(out + (size_t)n*D1))[2*c+1] = o1;
      float vv[8] = {o0.x,o0.y,o0.z,o0.w,o1.x,o1.y,o1.z,o1.w};
      #pragma unroll
      for (int k = 0; k < 8; k++) {
        atomicAdd(&bnacc[8*c+k], vv[k]);
        atomicAdd(&bnacc[128+8*c+k], vv[k]*vv[k]);
      }
    }
  }
  __syncthreads();
  atomicAdd(&bn[t], bnacc[t]);
}

// ---------- agg2 persistent: 4 waves/block, fused BN stats ----------
__global__ __launch_bounds__(256) void k_agg2s(const int* begv, const int* endv, const int* srcs,
                                               const float2* asv, const float2* adv,
                                               const uint4* hx, const float* bias,
                                               float* out, float* bn /* 512: sum|sq */) {
  __shared__ float2 sp[4][2][64];
  __shared__ float bnacc[512];
  int t = threadIdx.x;
  bnacc[t] = 0.f; bnacc[256+t] = 0.f;
  __syncthreads();
  int wid = t >> 6, lane = t & 63;
  int el = lane >> 5, c = lane & 31, h = c >> 4;
  for (int n = blockIdx.x*4 + wid; n < NN; n += AGB*4) {
    float2 ad = adv[n];
    int beg = begv[n], end = endv[n];
    float a[8] = {0.f,0.f,0.f,0.f,0.f,0.f,0.f,0.f};
    float z0 = 0.f, z1 = 0.f;
    for (int cb = beg; cb < end; cb += 64) {
      int len = end - cb; if (len > 64) len = 64;
      if (lane < len) {
        int s = srcs[cb + lane];
        float2 as = asv[s];
        float e0 = as.x + ad.x, e1 = as.y + ad.y;
        e0 = e0 > 0.f ? e0 : SLOPE*e0;
        e1 = e1 > 0.f ? e1 : SLOPE*e1;
        float p0 = __expf(e0), p1 = __expf(e1);
        sp[wid][0][lane] = make_float2(__int_as_float(s), p0);
        sp[wid][1][lane] = make_float2(__int_as_float(s), p1);
        z0 += p0; z1 += p1;
      }
      __builtin_amdgcn_wave_barrier();
      for (int j = 0; j < len; j += 2) {
        int e = j + el;
        if (e < len) {
          float2 v = sp[wid][h][e];
          uint4 u = hx[(size_t)__float_as_int(v.x)*32 + c];
          float pj = v.y;
          a[0] += pj*bf16_lo(u.x); a[1] += pj*bf16_hi(u.x);
          a[2] += pj*bf16_lo(u.y); a[3] += pj*bf16_hi(u.y);
          a[4] += pj*bf16_lo(u.z); a[5] += pj*bf16_hi(u.z);
          a[6] += pj*bf16_lo(u.w); a[7] += pj*bf16_hi(u.w);
        }
      }
      __builtin_amdgcn_wave_barrier();
    }
    #pragma unroll
    for (int k = 0; k < 8; k++) a[k] += __shfl_down(a[k], 32);
    #pragma unroll
    for (int o = 1; o < 64; o <<= 1) { z0 += __shfl_xor(z0, o); z1 += __shfl_xor(z1, o); }
    if (lane < 32) {
      float inv = 1.f / (h ? z1 : z0);
      float4 b0 = ((const float4*)bias)[2*c];
      float4 b1 = ((const float4*)bias)[2*c+1];
      float4 o0 = { a[0]*inv + b0.x, a[1]*inv + b0.y, a[2]*inv + b0.z, a[3]*inv + b0.w };
      float4 o1 = { a[4]*inv + b1.x, a[5]*inv + b1.y, a[6]*inv + b1.z, a[7]*inv + b1.w };
      ((float4*)(out + (size_t)n*D2))[2*c]   = o0;
      ((float4*)(out + (size_t)n*D2))[2*c+1] = o1;
      float vv[8] = {o0.x,o0.y,o0.z,o0.w,o1.x,o1.y,o1.z,o1.w};
      #pragma unroll
      for (int k = 0; k < 8; k++) {
        atomicAdd(&bnacc[8*c+k], vv[k]);
        atomicAdd(&bnacc[256+8*c+k], vv[k]*vv[k]);
      }
    }
  }
  __syncthreads();
  atomicAdd(&bn[t], bnacc[t]);
  atomicAdd(&bn[256+t], bnacc[256+t]);
}

// ---------- BN2 apply + ReLU -> fp32 d_out ----------
__global__ void k_bnapply2(const float* x, const float* bnsum, const float* bnsq,
                           const float* gamma, const float* beta, float* out) {
  int i = blockIdx.x*blockDim.x + threadIdx.x;     // float4 index
  if (i >= NN*D2/4) return;
  int c = (i & 63) * 4;
  float4 v = ((const float4*)x)[i];
  float r[4] = {v.x, v.y, v.z, v.w};
  #pragma unroll
  for (int k = 0; k < 4; k++) {
    float mean = bnsum[c+k] * (1.f/NN);
    float var  = bnsq[c+k] * (1.f/NN) - mean*mean;
    float o = (r[k] - mean) * rsqrtf(var + EPSV) * gamma[c+k] + beta[c+k];
    r[k] = o > 0.f ? o : 0.f;
  }
  float4 o4 = {r[0], r[1], r[2], r[3]};
  ((float4*)out)[i] = o4;
}

// ---------- launcher ----------
extern "C" void kernel_launch(void* const* d_in, const int* in_sizes, int n_in,
                              void* d_out, int out_size, void* d_ws, size_t ws_size,
                              hipStream_t stream) {
  const float* x      = (const float*)d_in[0];
  const void*  ei     = d_in[1];
  const float* W1     = (const float*)d_in[2];
  const float* att_s1 = (const float*)d_in[3];
  const float* att_d1 = (const float*)d_in[4];
  const float* bias1  = (const float*)d_in[5];
  const float* gamma1 = (const float*)d_in[6];
  const float* beta1  = (const float*)d_in[7];
  const float* W2     = (const float*)d_in[8];
  const float* att_s2 = (const float*)d_in[9];
  const float* att_d2 = (const float*)d_in[10];
  const float* bias2  = (const float*)d_in[11];
  const float* gamma2 = (const float*)d_in[12];
  const float* beta2  = (const float*)d_in[13];

  char* p = (char*)d_ws;
  __hip_bfloat16* hx1b = (__hip_bfloat16*)p; p += (size_t)NN*D1*2;
  __hip_bfloat16* hx2b = (__hip_bfloat16*)p; p += (size_t)NN*D2*2;
  float* out1 = (float*)p; p += (size_t)NN*D1*4;
  float* out2 = (float*)p; p += (size_t)NN*D2*4;
  float2* as1 = (float2*)p; p += (size_t)NN*8;
  float2* ad1 = (float2*)p; p += (size_t)NN*8;
  float2* as2 = (float2*)p; p += (size_t)NN*8;
  float2* ad2 = (float2*)p; p += (size_t)NN*8;
  float* bn1  = (float*)p; p += 256*4;    // sum|sq layer1 (contiguous 768-float zero region)
  float* bn2  = (float*)p; p += 512*4;    // sum|sq layer2
  unsigned int* dpart = (unsigned int*)p; p += (size_t)NHIST*HCH*4;
  int* begv   = (int*)p; p += NN*4;
  int* endv   = (int*)p; p += NN*4;
  int* cursor = (int*)p; p += NN*4;
  int* gcount = (int*)p; p += 16*4;
  int* srcs   = (int*)p; p += (size_t)ET*4;

  const int SCB = (ET/4 + 255)/256;        // scatter blocks
  k_hist<<<NHIST, 256, HCH*4, stream>>>(ei, dpart, gcount);
  k_alloc<<<(NN+255)/256, 256, 0, stream>>>(dpart, begv, endv, cursor, gcount, bn1);
  k_gs<<<NT1 + SCB, 256, 0, stream>>>(x, W1, att_s1, att_d1, hx1b, as1, ad1,
                                      ei, cursor, srcs);

  k_agg1s<<<AGB, 256, 0, stream>>>(begv, endv, srcs, as1, ad1, (const uint4*)hx1b,
                                   bias1, out1, bn1);
  k_gemm2f<<<(NN+63)/64, 256, 0, stream>>>(out1, W2, bn1, bn1+128, gamma1, beta1,
                                           att_s2, att_d2, hx2b, as2, ad2);
  k_agg2s<<<AGB, 256, 0, stream>>>(begv, endv, srcs, as2, ad2, (const uint4*)hx2b,
                                   bias2, out2, bn2);
  k_bnapply2<<<(NN*D2/4 + 255)/256, 256, 0, stream>>>(out2, bn2, bn2+256, gamma2, beta2,
                                                      (float*)d_out);
}

// Round 12
// 251.657 us; speedup vs baseline: 1.3675x; 1.3675x over previous
//
#include <hip/hip_runtime.h>
#include <hip/hip_bf16.h>
#include <math.h>

#define NN 20000      // nodes
#define ER 640000     // raw edges
#define ET 660000     // edges incl. self loops
#define D1 128
#define D2 256
#define EPSV 1e-5f
#define SLOPE 0.2f
#define NT1 313       // ceil(NN/64) gemm1 row tiles
#define NHIST 64      // histogram units
#define HCH 10000     // edges per unit; per-node count <= 10000 < 65536 (ushort pack)

typedef __attribute__((ext_vector_type(8))) short bf16x8;
typedef __attribute__((ext_vector_type(4))) float f32x4;

// ---------- helpers ----------
__device__ __forceinline__ int detect64(const void* ei) {
  const int* p = (const int*)ei;
  return (p[1] | p[3] | p[5] | p[7]) == 0;
}
__device__ __forceinline__ int clampn(int v) { return v < 0 ? 0 : (v >= NN ? NN-1 : v); }
__device__ __forceinline__ float bf16_lo(unsigned int u){ return __uint_as_float(u<<16); }
__device__ __forceinline__ float bf16_hi(unsigned int u){ return __uint_as_float(u & 0xffff0000u); }

// ---------- degree histogram: 64 LDS-private ushort-packed units ----------
__global__ void k_hist(const void* ei, unsigned int* dpart, int* gcount) {
  extern __shared__ unsigned int hist[];     // HCH uints = 2 nodes/uint
  int db = blockIdx.x, t = threadIdx.x;
  if (db == 0 && t == 0) *gcount = 0;
  for (int i = t; i < HCH; i += 256) hist[i] = 0;
  __syncthreads();
  int base = db * HCH;
  if (detect64(ei)) {
    const long long* q = (const long long*)ei + ER;
    for (int i = base + t; i < base + HCH; i += 256) {
      int d = clampn((int)q[i]);
      atomicAdd(&hist[d>>1], 1u << ((d&1)*16));
    }
  } else {
    const int* q = (const int*)ei + ER;
    for (int i = base + t; i < base + HCH; i += 256) {
      int d = clampn(q[i]);
      atomicAdd(&hist[d>>1], 1u << ((d&1)*16));
    }
  }
  __syncthreads();
  for (int i = t; i < HCH; i += 256) dpart[(size_t)db*HCH + i] = hist[i];
}

// ---------- parallel segment allocator ----------
__global__ __launch_bounds__(256) void k_alloc(const unsigned int* dpart, int* begv, int* endv,
                                               int* cursor, int* gcount, float* bnz) {
  __shared__ int wsum[4], wbase[4];
  int gid = blockIdx.x*256 + threadIdx.x;
  if (gid < 768) bnz[gid] = 0.f;            // bns1|bnq1|bns2|bnq2
  int d = 0;
  if (gid < NN) {
    d = 1;                                   // self loop
    int half = (gid & 1) * 16;
    int idx = gid >> 1;
    for (int db = 0; db < NHIST; db++)
      d += (dpart[(size_t)db*HCH + idx] >> half) & 0xffff;
  }
  int lane = threadIdx.x & 63, w = threadIdx.x >> 6;
  int v = d;
  #pragma unroll
  for (int o = 1; o < 64; o <<= 1) {
    int u = __shfl_up(v, o);
    if (lane >= o) v += u;
  }
  if (lane == 63) wsum[w] = v;
  __syncthreads();
  if (threadIdx.x == 0) {
    int s0 = wsum[0], s1 = wsum[1], s2 = wsum[2], s3 = wsum[3];
    int b = atomicAdd(gcount, s0 + s1 + s2 + s3);
    wbase[0] = b; wbase[1] = b + s0; wbase[2] = b + s0 + s1; wbase[3] = b + s0 + s1 + s2;
  }
  __syncthreads();
  if (gid < NN) {
    int beg = wbase[w] + v - d;
    begv[gid] = beg; cursor[gid] = beg; endv[gid] = beg + d;
  }
}

// ---------- merged: gemm1 tiles (inline W1 cast) + scatter ----------
__global__ __launch_bounds__(256) void k_gs(const float* x, const float* W1,
                                            const float* att_s1, const float* att_d1,
                                            __hip_bfloat16* hxb, float2* as1, float2* ad1,
                                            const void* ei, int* cursor, int* srcs) {
  __shared__ __hip_bfloat16 As[64][72];
  __shared__ __hip_bfloat16 Bs[128][72];
  __shared__ float asred[4][64], adred[4][64];
  int b = blockIdx.x, t = threadIdx.x;
  if (b >= NT1) {
    // ------- scatter role -------
    int i0 = ((b - NT1)*256 + t)*4;
    if (i0 >= ET) return;
    int s[4], d[4];
    if (i0 >= ER) {
      #pragma unroll
      for (int k = 0; k < 4; k++) { s[k] = i0 + k - ER; d[k] = s[k]; }
    } else if (detect64(ei)) {
      const long long* p64 = (const long long*)ei;
      uint4 qa = *(const uint4*)(p64 + i0);
      uint4 qb = *(const uint4*)(p64 + i0 + 2);
      uint4 ra = *(const uint4*)(p64 + ER + i0);
      uint4 rb = *(const uint4*)(p64 + ER + i0 + 2);
      s[0]=clampn((int)qa.x); s[1]=clampn((int)qa.z); s[2]=clampn((int)qb.x); s[3]=clampn((int)qb.z);
      d[0]=clampn((int)ra.x); d[1]=clampn((int)ra.z); d[2]=clampn((int)rb.x); d[3]=clampn((int)rb.z);
    } else {
      const int* p32 = (const int*)ei;
      uint4 qs = *(const uint4*)(p32 + i0);
      uint4 qd = *(const uint4*)(p32 + ER + i0);
      s[0]=clampn((int)qs.x); s[1]=clampn((int)qs.y); s[2]=clampn((int)qs.z); s[3]=clampn((int)qs.w);
      d[0]=clampn((int)qd.x); d[1]=clampn((int)qd.y); d[2]=clampn((int)qd.z); d[3]=clampn((int)qd.w);
    }
    #pragma unroll
    for (int k = 0; k < 4; k++) {
      int pos = atomicAdd(&cursor[d[k]], 1);
      srcs[pos] = s[k];
    }
    return;
  }
  // ------- gemm1 role -------
  int m0 = b * 64;
  for (int i = t; i < 512; i += 256) {       // stage x fp32->bf16
    int r = i >> 3, s = i & 7;
    int gr = m0 + r; if (gr >= NN) gr = NN - 1;
    float4 f0 = ((const float4*)(x + (size_t)gr*64))[s*2];
    float4 f1 = ((const float4*)(x + (size_t)gr*64))[s*2+1];
    __hip_bfloat16 hb[8] = {
      __float2bfloat16(f0.x), __float2bfloat16(f0.y), __float2bfloat16(f0.z), __float2bfloat16(f0.w),
      __float2bfloat16(f1.x), __float2bfloat16(f1.y), __float2bfloat16(f1.z), __float2bfloat16(f1.w)};
    *(uint4*)&As[r][s*8] = *(uint4*)hb;
  }
  for (int i = t; i < 8192; i += 256) {      // Bs[n][k] = bf16(W1[k][n]) inline transpose-cast
    int n = i & 127, k = i >> 7;
    Bs[n][k] = __float2bfloat16(W1[k*128 + n]);
  }
  __syncthreads();
  int w = t >> 6, lane = t & 63, lm = lane & 15, q = lane >> 4;
  f32x4 acc[4][2];
  #pragma unroll
  for (int rt = 0; rt < 4; rt++)
    #pragma unroll
    for (int ct = 0; ct < 2; ct++) acc[rt][ct] = (f32x4){0.f,0.f,0.f,0.f};
  #pragma unroll
  for (int kc = 0; kc < 2; kc++) {
    bf16x8 bfr[2];
    #pragma unroll
    for (int ct = 0; ct < 2; ct++)
      bfr[ct] = *(const bf16x8*)&Bs[w*32 + ct*16 + lm][kc*32 + q*8];
    #pragma unroll
    for (int rt = 0; rt < 4; rt++) {
      bf16x8 a = *(const bf16x8*)&As[rt*16 + lm][kc*32 + q*8];
      acc[rt][0] = __builtin_amdgcn_mfma_f32_16x16x32_bf16(a, bfr[0], acc[rt][0], 0, 0, 0);
      acc[rt][1] = __builtin_amdgcn_mfma_f32_16x16x32_bf16(a, bfr[1], acc[rt][1], 0, 0, 0);
    }
  }
  #pragma unroll
  for (int rt = 0; rt < 4; rt++)
    #pragma unroll
    for (int ct = 0; ct < 2; ct++)
      #pragma unroll
      for (int rg = 0; rg < 4; rg++) {
        int row = m0 + rt*16 + q*4 + rg;
        int col = w*32 + ct*16 + lm;
        if (row < NN) hxb[(size_t)row*128 + col] = __float2bfloat16(acc[rt][ct][rg]);
      }
  float asc[2], adc[2];
  #pragma unroll
  for (int ct = 0; ct < 2; ct++) {
    int col = w*32 + ct*16 + lm;
    asc[ct] = att_s1[col]; adc[ct] = att_d1[col];
  }
  #pragma unroll
  for (int rt = 0; rt < 4; rt++)
    #pragma unroll
    for (int rg = 0; rg < 4; rg++) {
      float ps = acc[rt][0][rg]*asc[0] + acc[rt][1][rg]*asc[1];
      float pd = acc[rt][0][rg]*adc[0] + acc[rt][1][rg]*adc[1];
      #pragma unroll
      for (int o = 1; o < 16; o <<= 1) { ps += __shfl_xor(ps, o); pd += __shfl_xor(pd, o); }
      if (lm == 0) { int row = rt*16 + q*4 + rg; asred[w][row] = ps; adred[w][row] = pd; }
    }
  __syncthreads();
  if (t < 64) {
    int row = m0 + t;
    if (row < NN) {
      as1[row] = make_float2(asred[0][t] + asred[1][t], asred[2][t] + asred[3][t]);
      ad1[row] = make_float2(adred[0][t] + adred[1][t], adred[2][t] + adred[3][t]);
    }
  }
}

// ---------- MFMA GEMM2: out1 -> BN1+ReLU+cast -> @W2 (inline cast) -> hx2b + att2 ----------
__global__ __launch_bounds__(256) void k_gemm2f(const float* out1, const float* W2,
                                                const float* bns1, const float* bnq1,
                                                const float* gamma1, const float* beta1,
                                                const float* att_s2, const float* att_d2,
                                                __hip_bfloat16* hxb, float2* as2, float2* ad2) {
  __shared__ __hip_bfloat16 As[64][136];
  __shared__ __hip_bfloat16 Bs[256][40];
  __shared__ float AB[2][128];
  __shared__ float asred[4][64], adred[4][64];
  int t = threadIdx.x;
  int m0 = blockIdx.x * 64;
  if (t < 128) {
    float mean = bns1[t]*(1.f/NN);
    float var  = bnq1[t]*(1.f/NN) - mean*mean;
    float A = rsqrtf(var + EPSV)*gamma1[t];
    AB[0][t] = A; AB[1][t] = beta1[t] - mean*A;
  }
  __syncthreads();
  for (int i = t; i < 1024; i += 256) {
    int r = i >> 4, s = i & 15;
    int gr = m0 + r; if (gr >= NN) gr = NN - 1;
    float4 f0 = ((const float4*)(out1 + (size_t)gr*128))[s*2];
    float4 f1 = ((const float4*)(out1 + (size_t)gr*128))[s*2+1];
    int c = s*8;
    float v[8] = {f0.x,f0.y,f0.z,f0.w,f1.x,f1.y,f1.z,f1.w};
    __hip_bfloat16 hb[8];
    #pragma unroll
    for (int k = 0; k < 8; k++)
      hb[k] = __float2bfloat16(fmaxf(v[k]*AB[0][c+k] + AB[1][c+k], 0.f));
    *(uint4*)&As[r][s*8] = *(uint4*)hb;
  }
  int w = t >> 6, lane = t & 63, lm = lane & 15, q = lane >> 4;
  f32x4 acc[4][4];
  #pragma unroll
  for (int rt = 0; rt < 4; rt++)
    #pragma unroll
    for (int ct = 0; ct < 4; ct++) acc[rt][ct] = (f32x4){0.f,0.f,0.f,0.f};
  for (int kc = 0; kc < 4; kc++) {
    __syncthreads();
    for (int i = t; i < 8192; i += 256) {     // Bs[n][kk] = bf16(W2[kc*32+kk][n])
      int n = i & 255, kk = i >> 8;
      Bs[n][kk] = __float2bfloat16(W2[(kc*32 + kk)*256 + n]);
    }
    __syncthreads();
    bf16x8 bfr[4];
    #pragma unroll
    for (int ct = 0; ct < 4; ct++)
      bfr[ct] = *(const bf16x8*)&Bs[w*64 + ct*16 + lm][q*8];
    #pragma unroll
    for (int rt = 0; rt < 4; rt++) {
      bf16x8 a = *(const bf16x8*)&As[rt*16 + lm][kc*32 + q*8];
      #pragma unroll
      for (int ct = 0; ct < 4; ct++)
        acc[rt][ct] = __builtin_amdgcn_mfma_f32_16x16x32_bf16(a, bfr[ct], acc[rt][ct], 0, 0, 0);
    }
  }
  #pragma unroll
  for (int rt = 0; rt < 4; rt++)
    #pragma unroll
    for (int ct = 0; ct < 4; ct++)
      #pragma unroll
      for (int rg = 0; rg < 4; rg++) {
        int row = m0 + rt*16 + q*4 + rg;
        int col = w*64 + ct*16 + lm;
        if (row < NN) hxb[(size_t)row*256 + col] = __float2bfloat16(acc[rt][ct][rg]);
      }
  float asc[4], adc[4];
  #pragma unroll
  for (int ct = 0; ct < 4; ct++) {
    int col = w*64 + ct*16 + lm;
    asc[ct] = att_s2[col]; adc[ct] = att_d2[col];
  }
  #pragma unroll
  for (int rt = 0; rt < 4; rt++)
    #pragma unroll
    for (int rg = 0; rg < 4; rg++) {
      float ps = acc[rt][0][rg]*asc[0] + acc[rt][1][rg]*asc[1]
               + acc[rt][2][rg]*asc[2] + acc[rt][3][rg]*asc[3];
      float pd = acc[rt][0][rg]*adc[0] + acc[rt][1][rg]*adc[1]
               + acc[rt][2][rg]*adc[2] + acc[rt][3][rg]*adc[3];
      #pragma unroll
      for (int o = 1; o < 16; o <<= 1) { ps += __shfl_xor(ps, o); pd += __shfl_xor(pd, o); }
      if (lm == 0) { int row = rt*16 + q*4 + rg; asred[w][row] = ps; adred[w][row] = pd; }
    }
  __syncthreads();
  if (t < 64) {
    int row = m0 + t;
    if (row < NN) {
      as2[row] = make_float2(asred[0][t] + asred[1][t], asred[2][t] + asred[3][t]);
      ad2[row] = make_float2(adred[0][t] + adred[1][t], adred[2][t] + adred[3][t]);
    }
  }
}

// ---------- agg layer1: 64 threads; 16 lanes/edge x uint4, 4 edge slots ----------
__global__ __launch_bounds__(64) void k_agg1(const int* begv, const int* endv, const int* srcs,
                                             const float2* asv, const float2* adv,
                                             const uint4* hx, const float* bias, float* out) {
  __shared__ float2 sp[2][64];
  int n = blockIdx.x, t = threadIdx.x;
  int el = t >> 4, c = t & 15;
  int h = c >> 3;
  float2 ad = adv[n];
  int beg = begv[n], end = endv[n];
  float a[8] = {0.f,0.f,0.f,0.f,0.f,0.f,0.f,0.f};
  float z0 = 0.f, z1 = 0.f;
  for (int cb = beg; cb < end; cb += 64) {
    int len = end - cb; if (len > 64) len = 64;
    if (t < len) {
      int s = srcs[cb + t];
      float2 as = asv[s];
      float e0 = as.x + ad.x, e1 = as.y + ad.y;
      e0 = e0 > 0.f ? e0 : SLOPE*e0;
      e1 = e1 > 0.f ? e1 : SLOPE*e1;
      float p0 = __expf(e0), p1 = __expf(e1);
      sp[0][t] = make_float2(__int_as_float(s), p0);
      sp[1][t] = make_float2(__int_as_float(s), p1);
      z0 += p0; z1 += p1;
    }
    __syncthreads();
    for (int j = 0; j < len; j += 4) {
      int e = j + el;
      if (e < len) {
        float2 v = sp[h][e];
        uint4 u = hx[(size_t)__float_as_int(v.x)*16 + c];
        float pj = v.y;
        a[0] += pj*bf16_lo(u.x); a[1] += pj*bf16_hi(u.x);
        a[2] += pj*bf16_lo(u.y); a[3] += pj*bf16_hi(u.y);
        a[4] += pj*bf16_lo(u.z); a[5] += pj*bf16_hi(u.z);
        a[6] += pj*bf16_lo(u.w); a[7] += pj*bf16_hi(u.w);
      }
    }
    __syncthreads();
  }
  #pragma unroll
  for (int k = 0; k < 8; k++) {
    a[k] += __shfl_down(a[k], 32);
    a[k] += __shfl_down(a[k], 16);
  }
  #pragma unroll
  for (int o = 1; o < 64; o <<= 1) { z0 += __shfl_xor(z0, o); z1 += __shfl_xor(z1, o); }
  if (t < 16) {
    float inv = 1.f / (h ? z1 : z0);
    float4 b0 = ((const float4*)bias)[2*c];
    float4 b1 = ((const float4*)bias)[2*c+1];
    float4 o0 = { a[0]*inv + b0.x, a[1]*inv + b0.y, a[2]*inv + b0.z, a[3]*inv + b0.w };
    float4 o1 = { a[4]*inv + b1.x, a[5]*inv + b1.y, a[6]*inv + b1.z, a[7]*inv + b1.w };
    ((float4*)(out + (size_t)n*D1))[2*c]   = o0;
    ((float4*)(out + (size_t)n*D1))[2*c+1] = o1;
  }
}

// ---------- agg layer2: 64 threads; 32 lanes/edge x uint4, 2 edge slots ----------
__global__ __launch_bounds__(64) void k_agg2(const int* begv, const int* endv, const int* srcs,
                                             const float2* asv, const float2* adv,
                                             const uint4* hx, const float* bias, float* out) {
  __shared__ float2 sp[2][64];
  int n = blockIdx.x, t = threadIdx.x;
  int el = t >> 5, c = t & 31;
  int h = c >> 4;
  float2 ad = adv[n];
  int beg = begv[n], end = endv[n];
  float a[8] = {0.f,0.f,0.f,0.f,0.f,0.f,0.f,0.f};
  float z0 = 0.f, z1 = 0.f;
  for (int cb = beg; cb < end; cb += 64) {
    int len = end - cb; if (len > 64) len = 64;
    if (t < len) {
      int s = srcs[cb + t];
      float2 as = asv[s];
      float e0 = as.x + ad.x, e1 = as.y + ad.y;
      e0 = e0 > 0.f ? e0 : SLOPE*e0;
      e1 = e1 > 0.f ? e1 : SLOPE*e1;
      float p0 = __expf(e0), p1 = __expf(e1);
      sp[0][t] = make_float2(__int_as_float(s), p0);
      sp[1][t] = make_float2(__int_as_float(s), p1);
      z0 += p0; z1 += p1;
    }
    __syncthreads();
    for (int j = 0; j < len; j += 2) {
      int e = j + el;
      if (e < len) {
        float2 v = sp[h][e];
        uint4 u = hx[(size_t)__float_as_int(v.x)*32 + c];
        float pj = v.y;
        a[0] += pj*bf16_lo(u.x); a[1] += pj*bf16_hi(u.x);
        a[2] += pj*bf16_lo(u.y); a[3] += pj*bf16_hi(u.y);
        a[4] += pj*bf16_lo(u.z); a[5] += pj*bf16_hi(u.z);
        a[6] += pj*bf16_lo(u.w); a[7] += pj*bf16_hi(u.w);
      }
    }
    __syncthreads();
  }
  #pragma unroll
  for (int k = 0; k < 8; k++) a[k] += __shfl_down(a[k], 32);
  #pragma unroll
  for (int o = 1; o < 64; o <<= 1) { z0 += __shfl_xor(z0, o); z1 += __shfl_xor(z1, o); }
  if (t < 32) {
    float inv = 1.f / (h ? z1 : z0);
    float4 b0 = ((const float4*)bias)[2*c];
    float4 b1 = ((const float4*)bias)[2*c+1];
    float4 o0 = { a[0]*inv + b0.x, a[1]*inv + b0.y, a[2]*inv + b0.z, a[3]*inv + b0.w };
    float4 o1 = { a[4]*inv + b1.x, a[5]*inv + b1.y, a[6]*inv + b1.z, a[7]*inv + b1.w };
    ((float4*)(out + (size_t)n*D2))[2*c]   = o0;
    ((float4*)(out + (size_t)n*D2))[2*c+1] = o1;
  }
}

// ---------- batchnorm stats ----------
template<int D>
__global__ void k_bnstats(const float* x, float* bnsum, float* bnsq) {
  const int ROWS = 100;
  int c = threadIdx.x;
  int r0 = blockIdx.x * ROWS;
  float s = 0.f, s2 = 0.f;
  for (int r = 0; r < ROWS; r++) {
    float v = x[(size_t)(r0 + r)*D + c];
    s += v; s2 += v*v;
  }
  atomicAdd(&bnsum[c], s);
  atomicAdd(&bnsq[c], s2);
}

// ---------- BN2 apply + ReLU -> fp32 d_out ----------
__global__ void k_bnapply2(const float* x, const float* bnsum, const float* bnsq,
                           const float* gamma, const float* beta, float* out) {
  int i = blockIdx.x*blockDim.x + threadIdx.x;     // float4 index
  if (i >= NN*D2/4) return;
  int c = (i & 63) * 4;
  float4 v = ((const float4*)x)[i];
  float r[4] = {v.x, v.y, v.z, v.w};
  #pragma unroll
  for (int k = 0; k < 4; k++) {
    float mean = bnsum[c+k] * (1.f/NN);
    float var  = bnsq[c+k] * (1.f/NN) - mean*mean;
    float o = (r[k] - mean) * rsqrtf(var + EPSV) * gamma[c+k] + beta[c+k];
    r[k] = o > 0.f ? o : 0.f;
  }
  float4 o4 = {r[0], r[1], r[2], r[3]};
  ((float4*)out)[i] = o4;
}

// ---------- launcher ----------
extern "C" void kernel_launch(void* const* d_in, const int* in_sizes, int n_in,
                              void* d_out, int out_size, void* d_ws, size_t ws_size,
                              hipStream_t stream) {
  const float* x      = (const float*)d_in[0];
  const void*  ei     = d_in[1];
  const float* W1     = (const float*)d_in[2];
  const float* att_s1 = (const float*)d_in[3];
  const float* att_d1 = (const float*)d_in[4];
  const float* bias1  = (const float*)d_in[5];
  const float* gamma1 = (const float*)d_in[6];
  const float* beta1  = (const float*)d_in[7];
  const float* W2     = (const float*)d_in[8];
  const float* att_s2 = (const float*)d_in[9];
  const float* att_d2 = (const float*)d_in[10];
  const float* bias2  = (const float*)d_in[11];
  const float* gamma2 = (const float*)d_in[12];
  const float* beta2  = (const float*)d_in[13];

  char* p = (char*)d_ws;
  __hip_bfloat16* hx1b = (__hip_bfloat16*)p; p += (size_t)NN*D1*2;
  __hip_bfloat16* hx2b = (__hip_bfloat16*)p; p += (size_t)NN*D2*2;
  float* out1 = (float*)p; p += (size_t)NN*D1*4;
  float* out2 = (float*)p; p += (size_t)NN*D2*4;
  float2* as1 = (float2*)p; p += (size_t)NN*8;
  float2* ad1 = (float2*)p; p += (size_t)NN*8;
  float2* as2 = (float2*)p; p += (size_t)NN*8;
  float2* ad2 = (float2*)p; p += (size_t)NN*8;
  float* bns1 = (float*)p; p += D1*4;     // contiguous zero region (768 floats)
  float* bnq1 = (float*)p; p += D1*4;
  float* bns2 = (float*)p; p += D2*4;
  float* bnq2 = (float*)p; p += D2*4;
  unsigned int* dpart = (unsigned int*)p; p += (size_t)NHIST*HCH*4;
  int* begv   = (int*)p; p += NN*4;
  int* endv   = (int*)p; p += NN*4;
  int* cursor = (int*)p; p += NN*4;
  int* gcount = (int*)p; p += 16*4;
  int* srcs   = (int*)p; p += (size_t)ET*4;

  const int SCB = (ET/4 + 255)/256;        // scatter blocks
  k_hist<<<NHIST, 256, HCH*4, stream>>>(ei, dpart, gcount);
  k_alloc<<<(NN+255)/256, 256, 0, stream>>>(dpart, begv, endv, cursor, gcount, bns1);
  k_gs<<<NT1 + SCB, 256, 0, stream>>>(x, W1, att_s1, att_d1, hx1b, as1, ad1,
                                      ei, cursor, srcs);

  k_agg1<<<NN, 64, 0, stream>>>(begv, endv, srcs, as1, ad1, (const uint4*)hx1b, bias1, out1);
  k_bnstats<D1><<<200, D1, 0, stream>>>(out1, bns1, bnq1);

  k_gemm2f<<<(NN+63)/64, 256, 0, stream>>>(out1, W2, bns1, bnq1, gamma1, beta1,
                                           att_s2, att_d2, hx2b, as2, ad2);
  k_agg2<<<NN, 64, 0, stream>>>(begv, endv, srcs, as2, ad2, (const uint4*)hx2b, bias2, out2);
  k_bnstats<D2><<<200, D2, 0, stream>>>(out2, bns2, bnq2);
  k_bnapply2<<<(NN*D2/4 + 255)/256, 256, 0, stream>>>(out2, bns2, bnq2, gamma2, beta2,
                                                      (float*)d_out);
}